// Round 11
// baseline (350.128 us; speedup 1.0000x reference)
//
#include <hip/hip_runtime.h>
#include <stdint.h>

#define T_STEPS 8
#define N_NODES 100000
#define E_EDGES 3200000
#define NB1 250
#define CHUNK 400          // NB1*CHUNK == N_NODES
#define NB3 391            // ceil(N/256)
#define NCAND_T 4000       // NB1*16 per t
#define NSLICE 8
#define ESLICE (E_EDGES / NSLICE)   // 400000
#define NRNG 8                      // owner r = row & 7
#define ACCN 12500                  // rows per owner: 100000/8 -> 50 KB LDS
#define SC_BLKS (T_STEPS * NSLICE * NRNG)  // 512 = 2 blocks/CU

// ---- bf16 pack/unpack (RNE) ----
__device__ __forceinline__ uint16_t f2bf(float x) {
    uint32_t b = __float_as_uint(x);
    b += 0x7FFFu + ((b >> 16) & 1u);
    return (uint16_t)(b >> 16);
}
__device__ __forceinline__ float bf2f(uint16_t u) {
    return __uint_as_float(((uint32_t)u) << 16);
}

// ---- sortable key: value desc, tie -> lower index ----
__device__ __forceinline__ unsigned long long make_key(float v, int idx) {
    uint32_t u = __float_as_uint(v);
    u = (u & 0x80000000u) ? ~u : (u | 0x80000000u);
    return (((unsigned long long)u) << 32) | (unsigned long long)(~(uint32_t)idx);
}
__device__ __forceinline__ float key_val(unsigned long long k) {
    uint32_t u = (uint32_t)(k >> 32);
    u = (u & 0x80000000u) ? (u & 0x7FFFFFFFu) : ~u;
    return __uint_as_float(u);
}
__device__ __forceinline__ int key_idx(unsigned long long k) {
    return (int)(~(uint32_t)(k & 0xFFFFFFFFu));
}

__device__ __forceinline__ unsigned long long shfl_xor_u64(unsigned long long x, int mask) {
    uint32_t lo = (uint32_t)x, hi = (uint32_t)(x >> 32);
    lo = __shfl_xor((unsigned int)lo, mask);
    hi = __shfl_xor((unsigned int)hi, mask);
    return (((unsigned long long)hi) << 32) | lo;
}

__device__ __forceinline__ void wave_argmax(unsigned long long& m, int& mp) {
    #pragma unroll
    for (int off = 32; off; off >>= 1) {
        unsigned long long o = shfl_xor_u64(m, off);
        int op = __shfl_xor(mp, off);
        if (o > m) { m = o; mp = op; }
    }
}

__device__ __forceinline__ float dot16(const float4* __restrict__ xr, const float* w) {
    float4 a = xr[0], b = xr[1], c = xr[2], d = xr[3];
    return a.x*w[0] + a.y*w[1] + a.z*w[2] + a.w*w[3]
         + b.x*w[4] + b.y*w[5] + b.z*w[6] + b.w*w[7]
         + c.x*w[8] + c.y*w[9] + c.z*w[10] + c.w*w[11]
         + d.x*w[12] + d.y*w[13] + d.z*w[14] + d.w*w[15];
}

// K1: for all t — y = (X_t @ p)/||p||, per-block top-16 candidates (sorted desc).
__global__ __launch_bounds__(256) void k_y_topk_all(const float* __restrict__ X,
                                                    const float* __restrict__ p,
                                                    unsigned long long* __restrict__ cand) {
    __shared__ unsigned long long keys[CHUNK];
    __shared__ unsigned long long wm[4];
    __shared__ int wp[4];
    int tid = threadIdx.x;
    int t = blockIdx.x / NB1;
    int b = blockIdx.x % NB1;
    const float* Xt = X + (size_t)t * N_NODES * 16;
    float pv[16];
    #pragma unroll
    for (int i = 0; i < 16; i++) pv[i] = p[i];
    float pn = 0.f;
    #pragma unroll
    for (int i = 0; i < 16; i++) pn += pv[i] * pv[i];
    float inv = 1.0f / sqrtf(pn);
    int base = b * CHUNK;
    for (int i = tid; i < CHUNK; i += 256) {
        int n = base + i;
        float y = dot16((const float4*)(Xt + (size_t)n * 16), pv) * inv;
        keys[i] = make_key(y, n);
    }
    __syncthreads();
    for (int k = 0; k < 16; k++) {
        unsigned long long m = 0ULL; int mp = -1;
        for (int i = tid; i < CHUNK; i += 256) {
            unsigned long long v = keys[i];
            if (v > m) { m = v; mp = i; }
        }
        wave_argmax(m, mp);
        if ((tid & 63) == 0) { wm[tid >> 6] = m; wp[tid >> 6] = mp; }
        __syncthreads();
        if (tid == 0) {
            unsigned long long best = wm[0]; int bp = wp[0];
            #pragma unroll
            for (int w2 = 1; w2 < 4; w2++) if (wm[w2] > best) { best = wm[w2]; bp = wp[w2]; }
            cand[(size_t)t * NCAND_T + b * 16 + k] = best;
            keys[bp] = 0ULL;
        }
        __syncthreads();
    }
}

// K2: one block, 512 threads = 8 waves. Wave w merges t=w's 250 sorted lists
// (k-way merge, heads in registers). Then batch-prefetch all Xs, then GRU chain.
__global__ __launch_bounds__(512) void k_merge_gru(
    const unsigned long long* __restrict__ cand,   // [8][4000]
    const float* __restrict__ X,                   // [8][N][16]
    const float* __restrict__ Winit,
    const float* __restrict__ W_Z, const float* __restrict__ U_Z, const float* __restrict__ B_Z,
    const float* __restrict__ W_R, const float* __restrict__ U_R, const float* __restrict__ B_R,
    const float* __restrict__ W_H, const float* __restrict__ U_H, const float* __restrict__ B_H,
    const float* __restrict__ lin_w,
    float* __restrict__ weff_g) {                  // [8][16]
    __shared__ float mWZ[256], mUZ[256], mBZ[256], mWR[256], mUR[256], mBR[256];
    __shared__ float mWH[256], mUH[256], mBH[256], mLW[16];
    __shared__ int   sidx[8][16];
    __shared__ float sval[8][16];
    __shared__ float Xs_all[8][16][16];   // [t][f][k]
    __shared__ float Wcur[16][16];
    __shared__ float RgW[16][16];
    int tid = threadIdx.x;
    if (tid < 256) {
        mWZ[tid] = W_Z[tid]; mUZ[tid] = U_Z[tid]; mBZ[tid] = B_Z[tid];
        mWR[tid] = W_R[tid]; mUR[tid] = U_R[tid]; mBR[tid] = B_R[tid];
        mWH[tid] = W_H[tid]; mUH[tid] = U_H[tid]; mBH[tid] = B_H[tid];
        Wcur[tid >> 4][tid & 15] = Winit[tid];
        if (tid < 16) mLW[tid] = lin_w[tid];
    }
    {
        int w = tid >> 6, lane = tid & 63;
        const unsigned long long* ct = cand + (size_t)w * NCAND_T;
        int cb = lane * 4;
        unsigned long long h0 = 0, h1 = 0, h2 = 0, h3 = 0;
        int p0 = 0, p1 = 0, p2 = 0, p3 = 0;
        if (cb + 0 < NB1) h0 = ct[(cb + 0) * 16];
        if (cb + 1 < NB1) h1 = ct[(cb + 1) * 16];
        if (cb + 2 < NB1) h2 = ct[(cb + 2) * 16];
        if (cb + 3 < NB1) h3 = ct[(cb + 3) * 16];
        for (int k = 0; k < 16; k++) {
            unsigned long long m = h0; int pay = (lane << 2) | 0;
            if (h1 > m) { m = h1; pay = (lane << 2) | 1; }
            if (h2 > m) { m = h2; pay = (lane << 2) | 2; }
            if (h3 > m) { m = h3; pay = (lane << 2) | 3; }
            wave_argmax(m, pay);
            if (lane == 0) { sidx[w][k] = key_idx(m); sval[w][k] = key_val(m); }
            if ((pay >> 2) == lane) {
                switch (pay & 3) {
                case 0: p0++; h0 = (p0 < 16) ? ct[(cb + 0) * 16 + p0] : 0ULL; break;
                case 1: p1++; h1 = (p1 < 16) ? ct[(cb + 1) * 16 + p1] : 0ULL; break;
                case 2: p2++; h2 = (p2 < 16) ? ct[(cb + 2) * 16 + p2] : 0ULL; break;
                default: p3++; h3 = (p3 < 16) ? ct[(cb + 3) * 16 + p3] : 0ULL; break;
                }
            }
        }
    }
    __syncthreads();
    // batched Xs prefetch for ALL t: 2048 scattered loads in flight at once
    for (int e = tid; e < 8 * 256; e += 512) {
        int tt = e >> 8, kk = (e >> 4) & 15, ff = e & 15;
        Xs_all[tt][ff][kk] = X[(size_t)tt * N_NODES * 16 + (size_t)sidx[tt][kk] * 16 + ff]
                           * sval[tt][kk];
    }
    __syncthreads();
    int i = (tid & 255) >> 4, j = tid & 15;
    for (int t = 0; t < T_STEPS; t++) {
        float Zg = 0.f, wn = 0.f;
        if (tid < 256) {
            float az = 0.f, ar = 0.f, uz = 0.f, ur = 0.f;
            #pragma unroll
            for (int m = 0; m < 16; m++) {
                az += mWZ[i * 16 + m] * Xs_all[t][m][j];
                ar += mWR[i * 16 + m] * Xs_all[t][m][j];
                uz += mUZ[i * 16 + m] * Wcur[m][j];
                ur += mUR[i * 16 + m] * Wcur[m][j];
            }
            Zg = 1.0f / (1.0f + expf(-(az + uz + mBZ[i * 16 + j])));
            float Rg = 1.0f / (1.0f + expf(-(ar + ur + mBR[i * 16 + j])));
            RgW[i][j] = Rg * Wcur[i][j];
        }
        __syncthreads();
        if (tid < 256) {
            float ah = 0.f, uh = 0.f;
            #pragma unroll
            for (int m = 0; m < 16; m++) {
                ah += mWH[i * 16 + m] * Xs_all[t][m][j];
                uh += mUH[i * 16 + m] * RgW[m][j];
            }
            float Ht = tanhf(ah + uh + mBH[i * 16 + j]);
            wn = (1.0f - Zg) * Wcur[i][j] + Zg * Ht;
        }
        __syncthreads();
        if (tid < 256) Wcur[i][j] = wn;
        __syncthreads();
        if (tid < 16) {
            float acc = 0.f;
            #pragma unroll
            for (int jj = 0; jj < 16; jj++) acc += Wcur[tid][jj] * mLW[jj];
            weff_g[t * 16 + tid] = acc;
        }
        __syncthreads();
    }
}

// K3: s[t][n] = X_t[n,:] . w_eff[t]
__global__ __launch_bounds__(256) void k_s_all(const float* __restrict__ X,
                                               const float* __restrict__ weff,
                                               float* __restrict__ s) {
    int t = blockIdx.x / NB3;
    int b = blockIdx.x % NB3;
    __shared__ float w[16];
    if (threadIdx.x < 16) w[threadIdx.x] = weff[t * 16 + threadIdx.x];
    __syncthreads();
    int n = b * 256 + threadIdx.x;
    if (n < N_NODES) {
        float v = dot16((const float4*)(X + ((size_t)t * N_NODES + n) * 16), w);
        s[(size_t)t * N_NODES + n] = v;
    }
}

// K4: fused LDS scatter, 8-way interleaved ownership (r = row&7, local = row>>3),
// 50 KB LDS -> TWO blocks per CU (32 waves, 2x TLP vs all prior rounds).
// Plain predicated loop — ILP scaffolding proven ineffective in R8-R10.
extern "C" __global__ __launch_bounds__(1024) void k_scatter_fused(
    const int* __restrict__ erow, const int* __restrict__ ecol,
    const float* __restrict__ evalv, const float* __restrict__ s,
    uint16_t* __restrict__ rep) {
    extern __shared__ float acc[];   // ACCN floats (50 KB)
    const int bid = blockIdx.x;
    const int t = bid & 7;           // one t per XCD (round-robin dispatch)
    const int m = bid >> 3;          // 0..63
    const int slice = m >> 3;        // 0..7
    const int r = m & 7;             // owner: row & 7 == r
    const int tid = threadIdx.x;
    for (int i = tid; i < ACCN; i += 1024) acc[i] = 0.f;
    __syncthreads();
    const float* __restrict__ st = s + (size_t)t * N_NODES;
    const size_t eb = (size_t)t * E_EDGES + (size_t)slice * ESLICE;
    const int4* __restrict__ r4 = (const int4*)(erow + eb);
    const int4* __restrict__ c4 = (const int4*)(ecol + eb);
    const float4* __restrict__ v4 = (const float4*)(evalv + eb);
    const int n4 = ESLICE / 4;       // 100000 packets

    for (int i = tid; i < n4; i += 1024) {
        int4 R = r4[i];
        int4 C = c4[i];
        float4 V = v4[i];
        if ((R.x & 7) == r) atomicAdd(&acc[R.x >> 3], V.x * st[C.x]);
        if ((R.y & 7) == r) atomicAdd(&acc[R.y >> 3], V.y * st[C.y]);
        if ((R.z & 7) == r) atomicAdd(&acc[R.z >> 3], V.z * st[C.z]);
        if ((R.w & 7) == r) atomicAdd(&acc[R.w >> 3], V.w * st[C.w]);
    }
    __syncthreads();
    const int seg = t * 64 + m;
    uint16_t* rp = rep + (size_t)seg * ACCN;
    for (int i = tid; i < ACCN; i += 1024) rp[i] = f2bf(acc[i]);
}

// K5: out[t][n] = lin_b + sum_slices rep ; owner r = n&7, local = n>>3
__global__ __launch_bounds__(256) void k_reduce_full(const uint16_t* __restrict__ rep,
                                                     const float* __restrict__ lin_b,
                                                     float* __restrict__ out) {
    int t = blockIdx.x / NB3;
    int b = blockIdx.x % NB3;
    int n = b * 256 + threadIdx.x;
    if (n >= N_NODES) return;
    int r = n & 7;
    int local = n >> 3;
    float acc = lin_b[0];
    #pragma unroll
    for (int sl = 0; sl < NSLICE; sl++) {
        int seg = t * 64 + sl * 8 + r;
        acc += bf2f(rep[(size_t)seg * ACCN + local]);
    }
    out[(size_t)t * N_NODES + n] = acc;
}

extern "C" void kernel_launch(void* const* d_in, const int* in_sizes, int n_in,
                              void* d_out, int out_size, void* d_ws, size_t ws_size,
                              hipStream_t stream) {
    const float* X     = (const float*)d_in[0];
    const int*   erow  = (const int*)d_in[1];
    const int*   ecol  = (const int*)d_in[2];
    const float* evalv = (const float*)d_in[3];
    const float* p     = (const float*)d_in[4];
    const float* W_Z   = (const float*)d_in[5];
    const float* U_Z   = (const float*)d_in[6];
    const float* B_Z   = (const float*)d_in[7];
    const float* W_R   = (const float*)d_in[8];
    const float* U_R   = (const float*)d_in[9];
    const float* B_R   = (const float*)d_in[10];
    const float* W_H   = (const float*)d_in[11];
    const float* U_H   = (const float*)d_in[12];
    const float* B_H   = (const float*)d_in[13];
    const float* Winit = (const float*)d_in[14];
    const float* lin_w = (const float*)d_in[15];
    const float* lin_b = (const float*)d_in[16];
    float* out = (float*)d_out;

    size_t dynLDS = (size_t)ACCN * sizeof(float);   // 50 KB -> 2 blocks/CU

    char* ws = (char*)d_ws;
    float* s    = (float*)ws;                                       // 3,200,000 B
    float* weff = (float*)(ws + 3200000);                           // 512 B
    unsigned long long* cand = (unsigned long long*)(ws + 3201024); // 256,000 B
    uint16_t* rep = (uint16_t*)(ws + 3457024);                      // 512*12500*2 = 12.8 MB

    k_y_topk_all<<<T_STEPS * NB1, 256, 0, stream>>>(X, p, cand);
    k_merge_gru<<<1, 512, 0, stream>>>(cand, X, Winit,
                                       W_Z, U_Z, B_Z, W_R, U_R, B_R, W_H, U_H, B_H,
                                       lin_w, weff);
    k_s_all<<<T_STEPS * NB3, 256, 0, stream>>>(X, weff, s);
    k_scatter_fused<<<SC_BLKS, 1024, dynLDS, stream>>>(erow, ecol, evalv, s, rep);
    k_reduce_full<<<T_STEPS * NB3, 256, 0, stream>>>(rep, lin_b, out);
}

// Round 12
// 259.966 us; speedup vs baseline: 1.3468x; 1.3468x over previous
//
#include <hip/hip_runtime.h>
#include <stdint.h>

#define T_STEPS 8
#define N_NODES 100000
#define E_EDGES 3200000
#define NB1 250
#define CHUNK 400          // NB1*CHUNK == N_NODES
#define NB3 391            // ceil(N/256)
#define NCAND_T 4000       // NB1*16 per t
#define NSLICE 8
#define ESLICE (E_EDGES / NSLICE)   // 400000
#define RNG_BITS 15
#define RNG (1 << RNG_BITS)         // 32768 -> 128 KB LDS
#define NRNG 4                      // ceil(100000/32768)
#define SC_BLKS (T_STEPS * NRNG * NSLICE)  // 256 = 1 block/CU

// ---- bf16 pack/unpack (RNE) ----
__device__ __forceinline__ uint16_t f2bf(float x) {
    uint32_t b = __float_as_uint(x);
    b += 0x7FFFu + ((b >> 16) & 1u);
    return (uint16_t)(b >> 16);
}
__device__ __forceinline__ float bf2f(uint16_t u) {
    return __uint_as_float(((uint32_t)u) << 16);
}

// ---- sortable key: value desc, tie -> lower index ----
__device__ __forceinline__ unsigned long long make_key(float v, int idx) {
    uint32_t u = __float_as_uint(v);
    u = (u & 0x80000000u) ? ~u : (u | 0x80000000u);
    return (((unsigned long long)u) << 32) | (unsigned long long)(~(uint32_t)idx);
}
__device__ __forceinline__ float key_val(unsigned long long k) {
    uint32_t u = (uint32_t)(k >> 32);
    u = (u & 0x80000000u) ? (u & 0x7FFFFFFFu) : ~u;
    return __uint_as_float(u);
}
__device__ __forceinline__ int key_idx(unsigned long long k) {
    return (int)(~(uint32_t)(k & 0xFFFFFFFFu));
}

__device__ __forceinline__ unsigned long long shfl_xor_u64(unsigned long long x, int mask) {
    uint32_t lo = (uint32_t)x, hi = (uint32_t)(x >> 32);
    lo = __shfl_xor((unsigned int)lo, mask);
    hi = __shfl_xor((unsigned int)hi, mask);
    return (((unsigned long long)hi) << 32) | lo;
}

__device__ __forceinline__ void wave_argmax(unsigned long long& m, int& mp) {
    #pragma unroll
    for (int off = 32; off; off >>= 1) {
        unsigned long long o = shfl_xor_u64(m, off);
        int op = __shfl_xor(mp, off);
        if (o > m) { m = o; mp = op; }
    }
}

__device__ __forceinline__ float dot16(const float4* __restrict__ xr, const float* w) {
    float4 a = xr[0], b = xr[1], c = xr[2], d = xr[3];
    return a.x*w[0] + a.y*w[1] + a.z*w[2] + a.w*w[3]
         + b.x*w[4] + b.y*w[5] + b.z*w[6] + b.w*w[7]
         + c.x*w[8] + c.y*w[9] + c.z*w[10] + c.w*w[11]
         + d.x*w[12] + d.y*w[13] + d.z*w[14] + d.w*w[15];
}

// K1: for all t — y = (X_t @ p)/||p||, per-block top-16 candidates (sorted desc).
__global__ __launch_bounds__(256) void k_y_topk_all(const float* __restrict__ X,
                                                    const float* __restrict__ p,
                                                    unsigned long long* __restrict__ cand) {
    __shared__ unsigned long long keys[CHUNK];
    __shared__ unsigned long long wm[4];
    __shared__ int wp[4];
    int tid = threadIdx.x;
    int t = blockIdx.x / NB1;
    int b = blockIdx.x % NB1;
    const float* Xt = X + (size_t)t * N_NODES * 16;
    float pv[16];
    #pragma unroll
    for (int i = 0; i < 16; i++) pv[i] = p[i];
    float pn = 0.f;
    #pragma unroll
    for (int i = 0; i < 16; i++) pn += pv[i] * pv[i];
    float inv = 1.0f / sqrtf(pn);
    int base = b * CHUNK;
    for (int i = tid; i < CHUNK; i += 256) {
        int n = base + i;
        float y = dot16((const float4*)(Xt + (size_t)n * 16), pv) * inv;
        keys[i] = make_key(y, n);
    }
    __syncthreads();
    for (int k = 0; k < 16; k++) {
        unsigned long long m = 0ULL; int mp = -1;
        for (int i = tid; i < CHUNK; i += 256) {
            unsigned long long v = keys[i];
            if (v > m) { m = v; mp = i; }
        }
        wave_argmax(m, mp);
        if ((tid & 63) == 0) { wm[tid >> 6] = m; wp[tid >> 6] = mp; }
        __syncthreads();
        if (tid == 0) {
            unsigned long long best = wm[0]; int bp = wp[0];
            #pragma unroll
            for (int w2 = 1; w2 < 4; w2++) if (wm[w2] > best) { best = wm[w2]; bp = wp[w2]; }
            cand[(size_t)t * NCAND_T + b * 16 + k] = best;
            keys[bp] = 0ULL;
        }
        __syncthreads();
    }
}

// K2: one block, 512 threads = 8 waves. Wave w merges t=w's 250 sorted lists
// (k-way merge, heads in registers). Then batch-prefetch all Xs, then GRU chain.
__global__ __launch_bounds__(512) void k_merge_gru(
    const unsigned long long* __restrict__ cand,   // [8][4000]
    const float* __restrict__ X,                   // [8][N][16]
    const float* __restrict__ Winit,
    const float* __restrict__ W_Z, const float* __restrict__ U_Z, const float* __restrict__ B_Z,
    const float* __restrict__ W_R, const float* __restrict__ U_R, const float* __restrict__ B_R,
    const float* __restrict__ W_H, const float* __restrict__ U_H, const float* __restrict__ B_H,
    const float* __restrict__ lin_w,
    float* __restrict__ weff_g) {                  // [8][16]
    __shared__ float mWZ[256], mUZ[256], mBZ[256], mWR[256], mUR[256], mBR[256];
    __shared__ float mWH[256], mUH[256], mBH[256], mLW[16];
    __shared__ int   sidx[8][16];
    __shared__ float sval[8][16];
    __shared__ float Xs_all[8][16][16];   // [t][f][k]
    __shared__ float Wcur[16][16];
    __shared__ float RgW[16][16];
    int tid = threadIdx.x;
    if (tid < 256) {
        mWZ[tid] = W_Z[tid]; mUZ[tid] = U_Z[tid]; mBZ[tid] = B_Z[tid];
        mWR[tid] = W_R[tid]; mUR[tid] = U_R[tid]; mBR[tid] = B_R[tid];
        mWH[tid] = W_H[tid]; mUH[tid] = U_H[tid]; mBH[tid] = B_H[tid];
        Wcur[tid >> 4][tid & 15] = Winit[tid];
        if (tid < 16) mLW[tid] = lin_w[tid];
    }
    {
        int w = tid >> 6, lane = tid & 63;
        const unsigned long long* ct = cand + (size_t)w * NCAND_T;
        int cb = lane * 4;
        unsigned long long h0 = 0, h1 = 0, h2 = 0, h3 = 0;
        int p0 = 0, p1 = 0, p2 = 0, p3 = 0;
        if (cb + 0 < NB1) h0 = ct[(cb + 0) * 16];
        if (cb + 1 < NB1) h1 = ct[(cb + 1) * 16];
        if (cb + 2 < NB1) h2 = ct[(cb + 2) * 16];
        if (cb + 3 < NB1) h3 = ct[(cb + 3) * 16];
        for (int k = 0; k < 16; k++) {
            unsigned long long m = h0; int pay = (lane << 2) | 0;
            if (h1 > m) { m = h1; pay = (lane << 2) | 1; }
            if (h2 > m) { m = h2; pay = (lane << 2) | 2; }
            if (h3 > m) { m = h3; pay = (lane << 2) | 3; }
            wave_argmax(m, pay);
            if (lane == 0) { sidx[w][k] = key_idx(m); sval[w][k] = key_val(m); }
            if ((pay >> 2) == lane) {
                switch (pay & 3) {
                case 0: p0++; h0 = (p0 < 16) ? ct[(cb + 0) * 16 + p0] : 0ULL; break;
                case 1: p1++; h1 = (p1 < 16) ? ct[(cb + 1) * 16 + p1] : 0ULL; break;
                case 2: p2++; h2 = (p2 < 16) ? ct[(cb + 2) * 16 + p2] : 0ULL; break;
                default: p3++; h3 = (p3 < 16) ? ct[(cb + 3) * 16 + p3] : 0ULL; break;
                }
            }
        }
    }
    __syncthreads();
    // batched Xs prefetch for ALL t: 2048 scattered loads in flight at once
    for (int e = tid; e < 8 * 256; e += 512) {
        int tt = e >> 8, kk = (e >> 4) & 15, ff = e & 15;
        Xs_all[tt][ff][kk] = X[(size_t)tt * N_NODES * 16 + (size_t)sidx[tt][kk] * 16 + ff]
                           * sval[tt][kk];
    }
    __syncthreads();
    int i = (tid & 255) >> 4, j = tid & 15;
    for (int t = 0; t < T_STEPS; t++) {
        float Zg = 0.f, wn = 0.f;
        if (tid < 256) {
            float az = 0.f, ar = 0.f, uz = 0.f, ur = 0.f;
            #pragma unroll
            for (int m = 0; m < 16; m++) {
                az += mWZ[i * 16 + m] * Xs_all[t][m][j];
                ar += mWR[i * 16 + m] * Xs_all[t][m][j];
                uz += mUZ[i * 16 + m] * Wcur[m][j];
                ur += mUR[i * 16 + m] * Wcur[m][j];
            }
            Zg = 1.0f / (1.0f + expf(-(az + uz + mBZ[i * 16 + j])));
            float Rg = 1.0f / (1.0f + expf(-(ar + ur + mBR[i * 16 + j])));
            RgW[i][j] = Rg * Wcur[i][j];
        }
        __syncthreads();
        if (tid < 256) {
            float ah = 0.f, uh = 0.f;
            #pragma unroll
            for (int m = 0; m < 16; m++) {
                ah += mWH[i * 16 + m] * Xs_all[t][m][j];
                uh += mUH[i * 16 + m] * RgW[m][j];
            }
            float Ht = tanhf(ah + uh + mBH[i * 16 + j]);
            wn = (1.0f - Zg) * Wcur[i][j] + Zg * Ht;
        }
        __syncthreads();
        if (tid < 256) Wcur[i][j] = wn;
        __syncthreads();
        if (tid < 16) {
            float acc = 0.f;
            #pragma unroll
            for (int jj = 0; jj < 16; jj++) acc += Wcur[tid][jj] * mLW[jj];
            weff_g[t * 16 + tid] = acc;
        }
        __syncthreads();
    }
}

// K3: s[t][n] = X_t[n,:] . w_eff[t]
__global__ __launch_bounds__(256) void k_s_all(const float* __restrict__ X,
                                               const float* __restrict__ weff,
                                               float* __restrict__ s) {
    int t = blockIdx.x / NB3;
    int b = blockIdx.x % NB3;
    __shared__ float w[16];
    if (threadIdx.x < 16) w[threadIdx.x] = weff[t * 16 + threadIdx.x];
    __syncthreads();
    int n = b * 256 + threadIdx.x;
    if (n < N_NODES) {
        float v = dot16((const float4*)(X + ((size_t)t * N_NODES + n) * 16), w);
        s[(size_t)t * N_NODES + n] = v;
    }
}

// K4: fused LDS range-scatter (best-measured variant, R8: 216 µs). Two packets
// per iteration; sched_barrier(0) pins the 6 stream loads above the gathers and
// the gathers above the ds_adds. Gathers address-clamped; ds_adds predicated.
extern "C" __global__ __launch_bounds__(1024) void k_scatter_fused(
    const int* __restrict__ erow, const int* __restrict__ ecol,
    const float* __restrict__ evalv, const float* __restrict__ s,
    uint16_t* __restrict__ rep) {
    extern __shared__ float acc[];   // RNG floats
    const int bid = blockIdx.x;
    const int t = bid & 7;           // one t per XCD (round-robin dispatch)
    const int m = bid >> 3;          // 0..31
    const int slice = m >> 2;        // 0..7
    const int r = m & 3;             // 0..3
    const int base = r << RNG_BITS;
    const int tid = threadIdx.x;
    {
        float4* a4 = (float4*)acc;
        #pragma unroll
        for (int q = 0; q < RNG / 4 / 1024; q++)
            a4[tid + q * 1024] = make_float4(0.f, 0.f, 0.f, 0.f);
    }
    __syncthreads();
    const float* __restrict__ st = s + (size_t)t * N_NODES;
    const size_t eb = (size_t)t * E_EDGES + (size_t)slice * ESLICE;
    const int4* __restrict__ r4 = (const int4*)(erow + eb);
    const int4* __restrict__ c4 = (const int4*)(ecol + eb);
    const float4* __restrict__ v4 = (const float4*)(evalv + eb);
    const int n4 = ESLICE / 4;       // 100000
    const int half = n4 / 2;         // 50000

    for (int i = tid; i < half; i += 1024) {
        // ---- phase 1: issue all 6 stream loads (pinned above gathers) ----
        int4   Ra = r4[i];          int4   Rb = r4[i + half];
        int4   Ca = c4[i];          int4   Cb = c4[i + half];
        float4 Va = v4[i];          float4 Vb = v4[i + half];
        __builtin_amdgcn_sched_barrier(0);
        // ---- phase 2: range tests + clamped gathers (8 more VMEM) ----
        int la0 = Ra.x - base, la1 = Ra.y - base, la2 = Ra.z - base, la3 = Ra.w - base;
        bool a0 = (unsigned)la0 < (unsigned)RNG, a1 = (unsigned)la1 < (unsigned)RNG,
             a2 = (unsigned)la2 < (unsigned)RNG, a3 = (unsigned)la3 < (unsigned)RNG;
        int lb0 = Rb.x - base, lb1 = Rb.y - base, lb2 = Rb.z - base, lb3 = Rb.w - base;
        bool b0 = (unsigned)lb0 < (unsigned)RNG, b1 = (unsigned)lb1 < (unsigned)RNG,
             b2 = (unsigned)lb2 < (unsigned)RNG, b3 = (unsigned)lb3 < (unsigned)RNG;
        float ga0 = st[a0 ? Ca.x : 0], ga1 = st[a1 ? Ca.y : 0],
              ga2 = st[a2 ? Ca.z : 0], ga3 = st[a3 ? Ca.w : 0];
        float gb0 = st[b0 ? Cb.x : 0], gb1 = st[b1 ? Cb.y : 0],
              gb2 = st[b2 ? Cb.z : 0], gb3 = st[b3 ? Cb.w : 0];
        __builtin_amdgcn_sched_barrier(0);
        // ---- phase 3: predicated LDS atomic adds (~1/3 lanes active) ----
        if (a0) atomicAdd(&acc[la0], Va.x * ga0);
        if (a1) atomicAdd(&acc[la1], Va.y * ga1);
        if (a2) atomicAdd(&acc[la2], Va.z * ga2);
        if (a3) atomicAdd(&acc[la3], Va.w * ga3);
        if (b0) atomicAdd(&acc[lb0], Vb.x * gb0);
        if (b1) atomicAdd(&acc[lb1], Vb.y * gb1);
        if (b2) atomicAdd(&acc[lb2], Vb.z * gb2);
        if (b3) atomicAdd(&acc[lb3], Vb.w * gb3);
    }
    __syncthreads();
    const int seg = t * 32 + m;
    ushort4* rp4 = (ushort4*)(rep + (size_t)seg * RNG);
    float4* a4 = (float4*)acc;
    #pragma unroll
    for (int q = 0; q < RNG / 4 / 1024; q++) {
        float4 a = a4[tid + q * 1024];
        ushort4 u;
        u.x = f2bf(a.x); u.y = f2bf(a.y); u.z = f2bf(a.z); u.w = f2bf(a.w);
        rp4[tid + q * 1024] = u;
    }
}

// K5: out[t][n] = lin_b + sum_slices rep ; seg = t*32 + sl*4 + r
__global__ __launch_bounds__(256) void k_reduce_full(const uint16_t* __restrict__ rep,
                                                     const float* __restrict__ lin_b,
                                                     float* __restrict__ out) {
    int t = blockIdx.x / NB3;
    int b = blockIdx.x % NB3;
    int n = b * 256 + threadIdx.x;
    if (n >= N_NODES) return;
    int r = n >> RNG_BITS;
    int local = n & (RNG - 1);
    float acc = lin_b[0];
    #pragma unroll
    for (int sl = 0; sl < NSLICE; sl++) {
        int seg = t * 32 + sl * 4 + r;
        acc += bf2f(rep[(size_t)seg * RNG + local]);
    }
    out[(size_t)t * N_NODES + n] = acc;
}

extern "C" void kernel_launch(void* const* d_in, const int* in_sizes, int n_in,
                              void* d_out, int out_size, void* d_ws, size_t ws_size,
                              hipStream_t stream) {
    const float* X     = (const float*)d_in[0];
    const int*   erow  = (const int*)d_in[1];
    const int*   ecol  = (const int*)d_in[2];
    const float* evalv = (const float*)d_in[3];
    const float* p     = (const float*)d_in[4];
    const float* W_Z   = (const float*)d_in[5];
    const float* U_Z   = (const float*)d_in[6];
    const float* B_Z   = (const float*)d_in[7];
    const float* W_R   = (const float*)d_in[8];
    const float* U_R   = (const float*)d_in[9];
    const float* B_R   = (const float*)d_in[10];
    const float* W_H   = (const float*)d_in[11];
    const float* U_H   = (const float*)d_in[12];
    const float* B_H   = (const float*)d_in[13];
    const float* Winit = (const float*)d_in[14];
    const float* lin_w = (const float*)d_in[15];
    const float* lin_b = (const float*)d_in[16];
    float* out = (float*)d_out;

    size_t dynLDS = (size_t)RNG * sizeof(float);   // 128 KB
    (void)hipFuncSetAttribute((const void*)k_scatter_fused,
                              hipFuncAttributeMaxDynamicSharedMemorySize,
                              (int)dynLDS);

    char* ws = (char*)d_ws;
    float* s    = (float*)ws;                                       // 3,200,000 B
    float* weff = (float*)(ws + 3200000);                           // 512 B
    unsigned long long* cand = (unsigned long long*)(ws + 3201024); // 256,000 B
    uint16_t* rep = (uint16_t*)(ws + 3457024);                      // 256*32768*2 = 16.8 MB

    k_y_topk_all<<<T_STEPS * NB1, 256, 0, stream>>>(X, p, cand);
    k_merge_gru<<<1, 512, 0, stream>>>(cand, X, Winit,
                                       W_Z, U_Z, B_Z, W_R, U_R, B_R, W_H, U_H, B_H,
                                       lin_w, weff);
    k_s_all<<<T_STEPS * NB3, 256, 0, stream>>>(X, weff, s);
    k_scatter_fused<<<SC_BLKS, 1024, dynLDS, stream>>>(erow, ecol, evalv, s, rep);
    k_reduce_full<<<T_STEPS * NB3, 256, 0, stream>>>(rep, lin_b, out);
}